// Round 7
// baseline (1271.264 us; speedup 1.0000x reference)
//
#include <hip/hip_runtime.h>
#include <hip/hip_bf16.h>

#define M_DIM 16384
#define N_DIM 8192
#define K_DIM 4096
#define NT (K_DIM / 64)  // 64 K-tiles, 32 groups of 2

typedef __attribute__((ext_vector_type(4))) float f32x4;
typedef __attribute__((ext_vector_type(16))) float f32x16;
typedef __attribute__((ext_vector_type(8))) __bf16 bf16x8;
typedef __attribute__((ext_vector_type(4))) unsigned short u16x4;

static __device__ __forceinline__ unsigned short f2bf(float f) {
  __bf16 h = (__bf16)f;
  return __builtin_bit_cast(unsigned short, h);
}

static __device__ __forceinline__ void gl_lds16(const unsigned short* g, unsigned short* l) {
  __builtin_amdgcn_global_load_lds(
      (const __attribute__((address_space(1))) unsigned int*)g,
      (__attribute__((address_space(3))) unsigned int*)l, 16, 0, 0);
}

// ---- prep: A [M][K] f32 -> bf16 (same layout) ----
__global__ void k_convert_a(const float* __restrict__ a, unsigned short* __restrict__ o) {
  const size_t n8 = (size_t)M_DIM * K_DIM / 8;
  for (size_t i = (size_t)blockIdx.x * blockDim.x + threadIdx.x; i < n8;
       i += (size_t)gridDim.x * blockDim.x) {
    const f32x4* p = (const f32x4*)(a + i * 8);
    f32x4 v0 = p[0];
    f32x4 v1 = p[1];
    u16x4 r0, r1;
#pragma unroll
    for (int j = 0; j < 4; ++j) { r0[j] = f2bf(v0[j]); r1[j] = f2bf(v1[j]); }
    *(u16x4*)(o + i * 8) = r0;
    *(u16x4*)(o + i * 8 + 4) = r1;
  }
}

// ---- prep: W [K][N] f32 -> Wt [N][K] bf16 (transpose + convert) ----
__global__ void k_convert_w_t(const float* __restrict__ w, unsigned short* __restrict__ wt) {
  __shared__ float tile[64][65];
  const int bk = blockIdx.y * 64;
  const int bn = blockIdx.x * 64;
  const int t = threadIdx.x;  // 256
  const int c4 = (t & 15) * 4;
  const int r = t >> 4;
#pragma unroll
  for (int p = 0; p < 4; ++p) {
    const int row = r + p * 16;
    f32x4 v = *(const f32x4*)&w[(size_t)(bk + row) * N_DIM + bn + c4];
    tile[row][c4 + 0] = v[0];
    tile[row][c4 + 1] = v[1];
    tile[row][c4 + 2] = v[2];
    tile[row][c4 + 3] = v[3];
  }
  __syncthreads();
#pragma unroll
  for (int p = 0; p < 4; ++p) {
    const int c = r + p * 16;
    u16x4 o;
#pragma unroll
    for (int j = 0; j < 4; ++j) o[j] = f2bf(tile[c4 + j][c]);
    *(u16x4*)&wt[(size_t)(bn + c) * K_DIM + bk + c4] = o;
  }
}

// ---- main GEMM: 256x256, BK=64, 8-phase/2-K-tile, 32x32x16 MFMA ----
// Shape swap vs r5: mfma_f32_32x32x16_bf16 (pipe ceiling 2495 TF vs 2176 for
// 16x16x32 [m119 vs m06]). Skeleton identical to r5: k-half LDS regions
// {Ak0,Ak1,Bk0,Bk1}x16KB x 2 bufs, reads 8/4/8/4, vmcnt(8) at odd phases,
// 2 barriers/phase. Per wave: 4x2 tiles of 32x32; acc[4][2] f32x16.
// Frags: row/col = lane&31, k = (lane>>5)*8 + ks*16 (ks=0..3 per K-tile).
// Swizzle: granule g = (ks&1)*2 + (lane>>5); phys = g ^ ((l31>>1)&3).
__global__ __launch_bounds__(512, 2) void k_gemm_8ph(
    const unsigned short* __restrict__ A, const unsigned short* __restrict__ Bt,
    const float* __restrict__ bias, float* __restrict__ C) {
  __shared__ __align__(16) unsigned short S[65536];  // 128 KB

  const int tid = threadIdx.x;
  const int lane = tid & 63;
  const int wave = tid >> 6;  // 0..7
  const int wm = wave >> 2;   // 0..1 -> 128-row half
  const int wn = wave & 3;    // 0..3 -> 64-col block
  const int l31 = lane & 31;
  const int lh = lane >> 5;   // 0..1

  // T1: XCD-aware bijective swizzle (2048 blocks, %8==0)
  const int bid = blockIdx.x;
  const int swz = (bid & 7) * 256 + (bid >> 3);
  const int local = swz & 255;
  const int tm = local & 63;
  const int tn = (swz >> 8) * 4 + (local >> 6);
  const int brow = tm * 256;
  const int bcol = tn * 256;

  // staging source: row = tid>>2 (+128 for 2nd gl_lds), dest granule tid&3,
  // source granule = dest ^ ((row>>1)&3) = dest ^ ((tid>>3)&3).
  const int srow2 = tid >> 2;
  const int sgel = ((tid & 3) ^ ((tid >> 3) & 3)) * 8;
  const unsigned short* aS = A + (size_t)(brow + srow2) * K_DIM + sgel;
  const unsigned short* bS = Bt + (size_t)(bcol + srow2) * K_DIM + sgel;

#define STG(reg, srcp, tt, kh)                                        \
  do {                                                                \
    unsigned short* d_ = S + ((tt)&1) * 32768 + (reg) + tid * 8;      \
    const unsigned short* g_ = (srcp) + (size_t)(tt)*64 + (kh)*32;    \
    gl_lds16(g_, d_);                                                 \
    gl_lds16(g_ + (size_t)128 * K_DIM, d_ + 4096);                    \
  } while (0)

  // frag-read swizzled granule offsets (elements within 32-elem row):
  // k-slot 0 -> granule lh, k-slot 1 -> granule 2+lh; XOR row bits (l31>>1)&3.
  const int xr = (l31 >> 1) & 3;
  const int swk0 = ((0 + lh) ^ xr) * 8;
  const int swk1 = ((2 + lh) ^ xr) * 8;
  const unsigned short* SA = S + (wm * 128 + l31) * 32;           // + X*32768 + kh*8192 + mi*1024 + swk
  const unsigned short* SB = S + 16384 + (wn * 64 + l31) * 32;    // + X*32768 + kh*8192 + ni*1024 + swk

  // dst[4]: [mi(2)][kslot(2)]; reads tiles mb+0,mb+1 of k-half kh, buf X
#define RD_A2(dst, X, kh, mb)                                                     \
  _Pragma("unroll") for (int mi_ = 0; mi_ < 2; ++mi_)                             \
      _Pragma("unroll") for (int ks_ = 0; ks_ < 2; ++ks_)                         \
          dst[mi_ * 2 + ks_] = *(const bf16x8*)(SA + (X)*32768 + (kh)*8192 +      \
                                                ((mb) + mi_) * 1024 +             \
                                                (ks_ ? swk1 : swk0));
#define RD_B2(dst, X, kh)                                                         \
  _Pragma("unroll") for (int ni_ = 0; ni_ < 2; ++ni_)                             \
      _Pragma("unroll") for (int ks_ = 0; ks_ < 2; ++ks_)                         \
          dst[ni_ * 2 + ks_] = *(const bf16x8*)(SB + (X)*32768 + (kh)*8192 +      \
                                                ni_ * 1024 + (ks_ ? swk1 : swk0));

  f32x16 acc[4][2] = {};

#define BAR __builtin_amdgcn_s_barrier()
#define LGKM0 asm volatile("s_waitcnt lgkmcnt(0)" ::: "memory")
#define SCHED0 __builtin_amdgcn_sched_barrier(0)
#define VMC(n) asm volatile("s_waitcnt vmcnt(" #n ")" ::: "memory")
  // 8 MFMA: 2mi x 2ni x 2ks, ks OUTER so same-acc updates are 4 insts apart
#define MFMA8(AP, MB, BP)                                                             \
  __builtin_amdgcn_s_setprio(1);                                                      \
  _Pragma("unroll") for (int ks_ = 0; ks_ < 2; ++ks_)                                 \
      _Pragma("unroll") for (int mi_ = 0; mi_ < 2; ++mi_)                             \
          _Pragma("unroll") for (int ni_ = 0; ni_ < 2; ++ni_)                         \
              acc[(MB) + mi_][ni_] = __builtin_amdgcn_mfma_f32_32x32x16_bf16(         \
                  AP[mi_ * 2 + ks_], BP[ni_ * 2 + ks_], acc[(MB) + mi_][ni_], 0, 0, 0); \
  __builtin_amdgcn_s_setprio(0)

  // ---- prologue: tile0 all 4 regions + {Ak0,Bk0}(1); drain tile0 k0 pair ----
  STG(0, aS, 0, 0);      // Ak0(0)
  STG(16384, bS, 0, 0);  // Bk0(0)
  STG(8192, aS, 0, 1);   // Ak1(0)
  STG(24576, bS, 0, 1);  // Bk1(0)
  STG(0, aS, 1, 0);      // Ak0(1)
  STG(16384, bS, 1, 0);  // Bk0(1)
  VMC(8);                // Ak0(0),Bk0(0) complete; 8 loads outstanding
  BAR;

  const int NTH = NT / 2;
  for (int it = 0; it < NTH; ++it) {
    const int u = 2 * it, v = u + 1;
    const bool pf = (it < NTH - 1);
    bf16x8 aL[4], aH[4], bA[4], bB[4];

    // ---- ph0: u kh0 mi0-1 (8 reads); stage Ak1(v) ----
    RD_A2(aL, 0, 0, 0); RD_B2(bA, 0, 0);
    STG(8192, aS, v, 1);
    BAR; LGKM0; SCHED0;
    MFMA8(aL, 0, bA);
    BAR;

    // ---- ph1: u kh0 mi2-3 (4 reads); stage Bk1(v); drain ----
    RD_A2(aH, 0, 0, 2);
    STG(24576, bS, v, 1);
    BAR; LGKM0; SCHED0;
    MFMA8(aH, 2, bA);
    VMC(8);  // drains Ak1(u),Bk1(u) (4 phases old)
    BAR;

    // ---- ph2: u kh1 mi0-1 (8 reads); stage Ak0(u+2) ----
    RD_A2(aL, 0, 1, 0); RD_B2(bB, 0, 1);
    if (pf) STG(0, aS, u + 2, 0);
    BAR; LGKM0; SCHED0;
    MFMA8(aL, 0, bB);
    BAR;

    // ---- ph3: u kh1 mi2-3 (4 reads); stage Bk0(u+2); drain ----
    RD_A2(aH, 0, 1, 2);
    if (pf) STG(16384, bS, u + 2, 0);
    BAR; LGKM0; SCHED0;
    MFMA8(aH, 2, bB);
    if (pf) { VMC(8); } else { VMC(4); }  // drains Ak0(v),Bk0(v)
    BAR;

    // ---- ph4: v kh0 mi0-1 (8 reads); stage Ak1(u+2) ----
    RD_A2(aL, 1, 0, 0); RD_B2(bA, 1, 0);
    if (pf) STG(8192, aS, u + 2, 1);
    BAR; LGKM0; SCHED0;
    MFMA8(aL, 0, bA);
    BAR;

    // ---- ph5: v kh0 mi2-3 (4 reads); stage Bk1(u+2); drain ----
    RD_A2(aH, 1, 0, 2);
    if (pf) STG(24576, bS, u + 2, 1);
    BAR; LGKM0; SCHED0;
    MFMA8(aH, 2, bA);
    if (pf) { VMC(8); } else { VMC(0); }  // drains Ak1(v),Bk1(v)
    BAR;

    // ---- ph6: v kh1 mi0-1 (8 reads); stage Ak0(v+2) ----
    RD_A2(aL, 1, 1, 0); RD_B2(bB, 1, 1);
    if (pf) STG(0, aS, v + 2, 0);
    BAR; LGKM0; SCHED0;
    MFMA8(aL, 0, bB);
    BAR;

    // ---- ph7: v kh1 mi2-3 (4 reads); stage Bk0(v+2); drain ----
    RD_A2(aH, 1, 1, 2);
    if (pf) STG(16384, bS, v + 2, 0);
    BAR; LGKM0; SCHED0;
    MFMA8(aH, 2, bB);
    if (pf) { VMC(8); }  // drains Ak0(u+2),Bk0(u+2)
    BAR;
  }
#undef STG
#undef RD_A2
#undef RD_B2
#undef MFMA8
#undef BAR
#undef LGKM0
#undef SCHED0
#undef VMC

  // ---- epilogue: 32x32 C/D: col = lane&31, row = (reg&3)+8*(reg>>2)+4*lh ----
#pragma unroll
  for (int mi = 0; mi < 4; ++mi) {
#pragma unroll
    for (int ni = 0; ni < 2; ++ni) {
      const int col = bcol + wn * 64 + ni * 32 + l31;
      const float bb = bias[col];
      const f32x16 t = acc[mi][ni];
      const int row0 = brow + wm * 128 + mi * 32 + 4 * lh;
#pragma unroll
      for (int reg = 0; reg < 16; ++reg) {
        const int row = row0 + (reg & 3) + 8 * (reg >> 2);
        C[(size_t)row * N_DIM + col] = t[reg] + bb;
      }
    }
  }
}

// ---- fallback (only if ws too small): fp32 LDS-tiled GEMM ----
__global__ __launch_bounds__(256) void k_gemm_f32(
    const float* __restrict__ A, const float* __restrict__ W,
    const float* __restrict__ bias, float* __restrict__ C) {
  __shared__ float As[64][17];
  __shared__ float Ws[16][64];
  const int tid = threadIdx.x;
  const int tx = tid & 15, ty = tid >> 4;
  const int brow = blockIdx.y * 64, bcol = blockIdx.x * 64;
  float acc[4][4] = {};
  for (int ks = 0; ks < K_DIM; ks += 16) {
    {
      const int m = tid >> 2, k = (tid & 3) * 4;
      f32x4 v = *(const f32x4*)&A[(size_t)(brow + m) * K_DIM + ks + k];
      As[m][k] = v[0]; As[m][k + 1] = v[1]; As[m][k + 2] = v[2]; As[m][k + 3] = v[3];
    }
    {
      const int k = tid >> 4, n = (tid & 15) * 4;
      *(f32x4*)&Ws[k][n] = *(const f32x4*)&W[(size_t)(ks + k) * N_DIM + bcol + n];
    }
    __syncthreads();
#pragma unroll
    for (int k = 0; k < 16; ++k) {
      float av[4], bv[4];
#pragma unroll
      for (int i = 0; i < 4; ++i) av[i] = As[ty * 4 + i][k];
#pragma unroll
      for (int j = 0; j < 4; ++j) bv[j] = Ws[k][tx * 4 + j];
#pragma unroll
      for (int i = 0; i < 4; ++i)
#pragma unroll
        for (int j = 0; j < 4; ++j) acc[i][j] += av[i] * bv[j];
    }
    __syncthreads();
  }
#pragma unroll
  for (int i = 0; i < 4; ++i) {
    const int row = brow + ty * 4 + i;
#pragma unroll
    for (int j = 0; j < 4; ++j) {
      const int col = bcol + tx * 4 + j;
      C[(size_t)row * N_DIM + col] = acc[i][j] + bias[col];
    }
  }
}

extern "C" void kernel_launch(void* const* d_in, const int* in_sizes, int n_in,
                              void* d_out, int out_size, void* d_ws, size_t ws_size,
                              hipStream_t stream) {
  const float* inp = (const float*)d_in[0];   // [16384, 4096]
  const float* w = (const float*)d_in[1];     // [4096, 8192]
  const float* bias = (const float*)d_in[2];  // [8192]
  float* out = (float*)d_out;                 // [16384, 8192]

  const size_t needA = (size_t)M_DIM * K_DIM * sizeof(unsigned short);  // 128 MB
  const size_t needW = (size_t)N_DIM * K_DIM * sizeof(unsigned short);  // 64 MB

  if (ws_size >= needA + needW) {
    unsigned short* Abf = (unsigned short*)d_ws;
    unsigned short* Wtb = (unsigned short*)((char*)d_ws + needA);
    k_convert_a<<<2048, 256, 0, stream>>>(inp, Abf);
    k_convert_w_t<<<dim3(N_DIM / 64, K_DIM / 64), 256, 0, stream>>>(w, Wtb);
    k_gemm_8ph<<<(M_DIM / 256) * (N_DIM / 256), 512, 0, stream>>>(Abf, Wtb, bias, out);
  } else {
    k_gemm_f32<<<dim3(N_DIM / 64, M_DIM / 64), 256, 0, stream>>>(inp, w, bias, out);
  }
}